// Round 11
// baseline (270.980 us; speedup 1.0000x reference)
//
#include <hip/hip_runtime.h>

#define NN 50000
#define NE 600000
#define HD 128
#define NG 512
#define OD 64
#define BN_EPS 1e-5f

#define SCAN_BLK 1024
#define NSB ((NN + SCAN_BLK - 1) / SCAN_BLK)  // 49
#define ECAP 1536   // LDS edge-index capacity (mean 768/block; fallback if exceeded)
#define NBANK 8     // stats atomic shards

typedef __attribute__((ext_vector_type(8))) short bf16x8;
typedef __attribute__((ext_vector_type(4))) float f32x4;

__device__ __forceinline__ unsigned short f2bf(float f) {
    unsigned u = __builtin_bit_cast(unsigned, f);
    unsigned r = u + 0x7FFFu + ((u >> 16) & 1u);  // round-to-nearest-even
    return (unsigned short)(r >> 16);
}

__device__ __forceinline__ float bflo(unsigned u) { return __builtin_bit_cast(float, u << 16); }
__device__ __forceinline__ float bfhi(unsigned u) { return __builtin_bit_cast(float, u & 0xffff0000u); }

__device__ __forceinline__ unsigned packbf2(float x, float y) {
    return (unsigned)f2bf(x) | ((unsigned)f2bf(y) << 16);
}

// ---------------- fp32 -> bf16 bulk converts ----------------

__global__ void cvt_kernel(const float* __restrict__ src, unsigned short* __restrict__ dst, int n8) {
    int i = blockIdx.x * blockDim.x + threadIdx.x;
    if (i >= n8) return;
    float4 a = ((const float4*)src)[2 * i];
    float4 b = ((const float4*)src)[2 * i + 1];
    uint4 o;
    o.x = packbf2(a.x, a.y);
    o.y = packbf2(a.z, a.w);
    o.z = packbf2(b.x, b.y);
    o.w = packbf2(b.z, b.w);
    ((uint4*)dst)[i] = o;
}

__global__ void cvt6_kernel(const float* __restrict__ s0, const float* __restrict__ s1,
                            const float* __restrict__ s2, const float* __restrict__ s3,
                            const float* __restrict__ s4, const float* __restrict__ s5,
                            unsigned short* __restrict__ dst) {
    int i = blockIdx.x * blockDim.x + threadIdx.x;  // 0 .. 6*2048-1
    const int wsel = i >> 11;
    const int o8 = i & 2047;
    const float* sp = (wsel == 0) ? s0 : (wsel == 1) ? s1 : (wsel == 2) ? s2
                    : (wsel == 3) ? s3 : (wsel == 4) ? s4 : s5;
    float4 a = ((const float4*)sp)[2 * o8];
    float4 b = ((const float4*)sp)[2 * o8 + 1];
    uint4 o;
    o.x = packbf2(a.x, a.y);
    o.y = packbf2(a.z, a.w);
    o.z = packbf2(b.x, b.y);
    o.w = packbf2(b.z, b.w);
    ((uint4*)(dst + (size_t)wsel * HD * HD))[o8] = o;
}

// ---------------- CSR build ----------------

__global__ void hist_kernel(const int* __restrict__ dst, int* __restrict__ deg, int E) {
    int i = blockIdx.x * blockDim.x + threadIdx.x;
    if (i < E) atomicAdd(&deg[dst[i]], 1);
}

__global__ void local_scan_kernel(const int* __restrict__ deg, int* __restrict__ lexcl,
                                  int* __restrict__ bsum, int n) {
    __shared__ int part[SCAN_BLK];
    const int tid = threadIdx.x;
    const int i = blockIdx.x * SCAN_BLK + tid;
    int v = (i < n) ? deg[i] : 0;
    part[tid] = v;
    __syncthreads();
    int incl = v;
    for (int off = 1; off < SCAN_BLK; off <<= 1) {
        int t = (tid >= off) ? part[tid - off] : 0;
        __syncthreads();
        incl += t;
        part[tid] = incl;
        __syncthreads();
    }
    if (i < n) lexcl[i] = incl - v;
    if (tid == SCAN_BLK - 1) bsum[blockIdx.x] = incl;
}

__global__ void scan_bsum_kernel(const int* __restrict__ bsum, int* __restrict__ boff,
                                 int* __restrict__ offsets, int nb, int n) {
    const int tid = threadIdx.x;  // 64 threads
    int orig = (tid < nb) ? bsum[tid] : 0;
    int v = orig;
    for (int off = 1; off < 64; off <<= 1) {
        int t = __shfl_up(v, off);
        if (tid >= off) v += t;
    }
    if (tid < nb) boff[tid] = v - orig;
    if (tid == 63) offsets[n] = v;  // total = E
}

__global__ void finalize_scan_kernel(const int* __restrict__ lexcl, const int* __restrict__ boff,
                                     int* __restrict__ offsets, int* __restrict__ cursor, int n) {
    int i = blockIdx.x * blockDim.x + threadIdx.x;
    if (i < n) {
        int o = lexcl[i] + boff[i >> 10];
        offsets[i] = o;
        cursor[i] = o;
    }
}

__global__ void fill_kernel(const int* __restrict__ src, const int* __restrict__ dst,
                            int* __restrict__ cursor, int* __restrict__ srcs, int E) {
    int i = blockIdx.x * blockDim.x + threadIdx.x;
    if (i < E) {
        int pos = atomicAdd(&cursor[dst[i]], 1);
        srcs[pos] = src[i];
    }
}

__global__ void gstart_kernel(const int* __restrict__ batch, int* __restrict__ gstart,
                              int n, int G) {
    int i = blockIdx.x * blockDim.x + threadIdx.x;
    if (i >= n) return;
    int b = batch[i];
    int bp = (i == 0) ? -1 : batch[i - 1];
    for (int g = bp + 1; g <= b; ++g) gstart[g] = i;
    if (i == n - 1) {
        for (int g = b + 1; g <= G; ++g) gstart[g] = n;
    }
}

// ---------------- fused GIN layer ----------------
// z_i = h_i + sum_{j in N(i)} h_j  (h already BN+relu'd; pure sum gather)
// C = relu(z @ Wa^T + ba) @ Wb^T + bb  -> bf16 out + sharded column stats.
// Gather: lanes in 4 groups x 16 chunks; one uint4 wave-load fetches 4 rows
// (1 KB). Nodes processed in PAIRS with both nodes' 8 loads issued before
// either accumulate -> 4 latency exposures per wave instead of 8.

__global__ __launch_bounds__(512) void fused_gin(const unsigned* __restrict__ hp,
                                                 const int* __restrict__ offsets,
                                                 const int* __restrict__ srcs,
                                                 const unsigned short* __restrict__ WaBf,
                                                 const float* __restrict__ ba,
                                                 const unsigned short* __restrict__ WbBf,
                                                 const float* __restrict__ bb,
                                                 unsigned short* __restrict__ Cb,
                                                 float* __restrict__ statsOut,
                                                 int nrows) {
    __shared__ short SB[64 * 136];
    __shared__ int elds[ECAP];
    __shared__ float sred[2][128][2];

    const int t = threadIdx.x;
    const int lane = t & 63;
    const int w = t >> 6;        // wave 0..7
    const int g16 = lane >> 4;   // item slot 0..3
    const int c16 = lane & 15;   // 16B chunk within row
    const int row0 = blockIdx.x * 64;

    const int rend = (row0 + 64 < nrows) ? row0 + 64 : nrows;
    const int ebase = offsets[row0];
    const int cnt = offsets[rend] - ebase;
    const bool fast = (cnt <= ECAP);

    if (fast) {
        for (int k = t; k < cnt; k += 512) elds[k] = srcs[ebase + k];
    }
    __syncthreads();

    auto ld4 = [&](int idx) -> uint4 {
        return ((const uint4*)(hp + (size_t)idx * 64))[c16];
    };

    // ---- gather: wave w owns rows w*8 .. w*8+7, two nodes per iteration
    for (int i = 0; i < 8; i += 2) {
        const int rA = w * 8 + i, rB = rA + 1;
        const int gA = row0 + rA, gB = row0 + rB;

        int itemsA = 0, itemsB = 0, jA = 0, jB = 0;
        if (gA < nrows) { jA = offsets[gA]; itemsA = offsets[gA + 1] - jA + 1; }
        if (gB < nrows) { jB = offsets[gB]; itemsB = offsets[gB + 1] - jB + 1; }

        float a0 = 0.f, a1 = 0.f, a2 = 0.f, a3 = 0.f, a4 = 0.f, a5 = 0.f, a6 = 0.f, a7 = 0.f;
        float b0 = 0.f, b1 = 0.f, b2 = 0.f, b3 = 0.f, b4 = 0.f, b5 = 0.f, b6 = 0.f, b7 = 0.f;

        auto accA = [&](uint4 v) {
            a0 += bflo(v.x); a1 += bfhi(v.x);
            a2 += bflo(v.y); a3 += bfhi(v.y);
            a4 += bflo(v.z); a5 += bfhi(v.z);
            a6 += bflo(v.w); a7 += bfhi(v.w);
        };
        auto accB = [&](uint4 v) {
            b0 += bflo(v.x); b1 += bfhi(v.x);
            b2 += bflo(v.y); b3 += bfhi(v.y);
            b4 += bflo(v.z); b5 += bfhi(v.z);
            b6 += bflo(v.w); b7 += bfhi(v.w);
        };

        if (fast) {
            const int j0A = jA - ebase, j0B = jB - ebase;
            uint4 va0 = {0, 0, 0, 0}, va1 = {0, 0, 0, 0}, va2 = {0, 0, 0, 0}, va3 = {0, 0, 0, 0};
            uint4 vb0 = {0, 0, 0, 0}, vb1 = {0, 0, 0, 0}, vb2 = {0, 0, 0, 0}, vb3 = {0, 0, 0, 0};
            // issue all 8 loads (predicated) before any accumulate
            { const int it = g16;      if (it < itemsA) va0 = ld4(it == 0 ? gA : elds[j0A + it - 1]); }
            { const int it = 4 + g16;  if (it < itemsA) va1 = ld4(elds[j0A + it - 1]); }
            { const int it = 8 + g16;  if (it < itemsA) va2 = ld4(elds[j0A + it - 1]); }
            { const int it = 12 + g16; if (it < itemsA) va3 = ld4(elds[j0A + it - 1]); }
            { const int it = g16;      if (it < itemsB) vb0 = ld4(it == 0 ? gB : elds[j0B + it - 1]); }
            { const int it = 4 + g16;  if (it < itemsB) vb1 = ld4(elds[j0B + it - 1]); }
            { const int it = 8 + g16;  if (it < itemsB) vb2 = ld4(elds[j0B + it - 1]); }
            { const int it = 12 + g16; if (it < itemsB) vb3 = ld4(elds[j0B + it - 1]); }
            accA(va0); accA(va1); accA(va2); accA(va3);
            accB(vb0); accB(vb1); accB(vb2); accB(vb3);
            // rare tails (items > 16)
            for (int base = 16; base < itemsA; base += 4) {
                const int it = base + g16;
                uint4 v = {0, 0, 0, 0};
                if (it < itemsA) v = ld4(elds[j0A + it - 1]);
                accA(v);
            }
            for (int base = 16; base < itemsB; base += 4) {
                const int it = base + g16;
                uint4 v = {0, 0, 0, 0};
                if (it < itemsB) v = ld4(elds[j0B + it - 1]);
                accB(v);
            }
        } else {
            for (int base = 0; base < itemsA; base += 4) {
                const int it = base + g16;
                uint4 v = {0, 0, 0, 0};
                if (it < itemsA) v = ld4(it == 0 ? gA : srcs[jA + it - 1]);
                accA(v);
            }
            for (int base = 0; base < itemsB; base += 4) {
                const int it = base + g16;
                uint4 v = {0, 0, 0, 0};
                if (it < itemsB) v = ld4(it == 0 ? gB : srcs[jB + it - 1]);
                accB(v);
            }
        }

        // combine the 4 lane-groups (both nodes)
        a0 += __shfl_xor(a0, 16); a1 += __shfl_xor(a1, 16);
        a2 += __shfl_xor(a2, 16); a3 += __shfl_xor(a3, 16);
        a4 += __shfl_xor(a4, 16); a5 += __shfl_xor(a5, 16);
        a6 += __shfl_xor(a6, 16); a7 += __shfl_xor(a7, 16);
        b0 += __shfl_xor(b0, 16); b1 += __shfl_xor(b1, 16);
        b2 += __shfl_xor(b2, 16); b3 += __shfl_xor(b3, 16);
        b4 += __shfl_xor(b4, 16); b5 += __shfl_xor(b5, 16);
        b6 += __shfl_xor(b6, 16); b7 += __shfl_xor(b7, 16);
        a0 += __shfl_xor(a0, 32); a1 += __shfl_xor(a1, 32);
        a2 += __shfl_xor(a2, 32); a3 += __shfl_xor(a3, 32);
        a4 += __shfl_xor(a4, 32); a5 += __shfl_xor(a5, 32);
        a6 += __shfl_xor(a6, 32); a7 += __shfl_xor(a7, 32);
        b0 += __shfl_xor(b0, 32); b1 += __shfl_xor(b1, 32);
        b2 += __shfl_xor(b2, 32); b3 += __shfl_xor(b3, 32);
        b4 += __shfl_xor(b4, 32); b5 += __shfl_xor(b5, 32);
        b6 += __shfl_xor(b6, 32); b7 += __shfl_xor(b7, 32);
        if (g16 == 0) {
            uint4 oA, oB;
            oA.x = packbf2(a0, a1); oA.y = packbf2(a2, a3);
            oA.z = packbf2(a4, a5); oA.w = packbf2(a6, a7);
            oB.x = packbf2(b0, b1); oB.y = packbf2(b2, b3);
            oB.z = packbf2(b4, b5); oB.w = packbf2(b6, b7);
            *(uint4*)&SB[rA * 136 + c16 * 8] = oA;
            *(uint4*)&SB[rB * 136 + c16 * 8] = oB;
        }
    }
    __syncthreads();  // SB holds A

    const int wr = w >> 2;     // row half (32 rows)
    const int wc = w & 3;      // col quarter (32 cols)
    const int l15 = lane & 15;
    const int l4 = lane >> 4;  // 0..3

    // ---- MFMA pass 1: t = A @ Wa^T
    f32x4 acc[2][2];
#pragma unroll
    for (int m = 0; m < 2; ++m)
#pragma unroll
        for (int n = 0; n < 2; ++n) acc[m][n] = (f32x4){0.f, 0.f, 0.f, 0.f};

#pragma unroll
    for (int kk = 0; kk < 4; ++kk) {
        bf16x8 af[2], bfr[2];
#pragma unroll
        for (int m = 0; m < 2; ++m)
            af[m] = *(const bf16x8*)&SB[(wr * 32 + m * 16 + l15) * 136 + kk * 32 + l4 * 8];
#pragma unroll
        for (int n = 0; n < 2; ++n)
            bfr[n] = *(const bf16x8*)(WaBf + (size_t)(wc * 32 + n * 16 + l15) * HD + kk * 32 + l4 * 8);
#pragma unroll
        for (int m = 0; m < 2; ++m)
#pragma unroll
            for (int n = 0; n < 2; ++n)
                acc[m][n] = __builtin_amdgcn_mfma_f32_16x16x32_bf16(af[m], bfr[n], acc[m][n], 0, 0, 0);
    }
    __syncthreads();  // pass-1 SB reads complete

    // epilogue 1: relu(t + ba) -> SB (as A2, bf16)
#pragma unroll
    for (int n = 0; n < 2; ++n) {
        const int col = wc * 32 + n * 16 + l15;
        const float bav = ba[col];
#pragma unroll
        for (int m = 0; m < 2; ++m) {
#pragma unroll
            for (int j = 0; j < 4; ++j) {
                const int row = wr * 32 + m * 16 + l4 * 4 + j;
                SB[row * 136 + col] = (short)f2bf(fmaxf(acc[m][n][j] + bav, 0.f));
            }
        }
    }
    __syncthreads();  // A2 visible

    // ---- MFMA pass 2: C = A2 @ Wb^T
#pragma unroll
    for (int m = 0; m < 2; ++m)
#pragma unroll
        for (int n = 0; n < 2; ++n) acc[m][n] = (f32x4){0.f, 0.f, 0.f, 0.f};

#pragma unroll
    for (int kk = 0; kk < 4; ++kk) {
        bf16x8 af[2], bfr[2];
#pragma unroll
        for (int m = 0; m < 2; ++m)
            af[m] = *(const bf16x8*)&SB[(wr * 32 + m * 16 + l15) * 136 + kk * 32 + l4 * 8];
#pragma unroll
        for (int n = 0; n < 2; ++n)
            bfr[n] = *(const bf16x8*)(WbBf + (size_t)(wc * 32 + n * 16 + l15) * HD + kk * 32 + l4 * 8);
#pragma unroll
        for (int m = 0; m < 2; ++m)
#pragma unroll
            for (int n = 0; n < 2; ++n)
                acc[m][n] = __builtin_amdgcn_mfma_f32_16x16x32_bf16(af[m], bfr[n], acc[m][n], 0, 0, 0);
    }

    // epilogue 2: Cb = bf16(acc + bb), plus per-column stats partials
    float st00 = 0.f, st01 = 0.f, st10 = 0.f, st11 = 0.f;
#pragma unroll
    for (int n = 0; n < 2; ++n) {
        const int col = wc * 32 + n * 16 + l15;
        const float bbv = bb[col];
#pragma unroll
        for (int m = 0; m < 2; ++m) {
#pragma unroll
            for (int j = 0; j < 4; ++j) {
                const int row = row0 + wr * 32 + m * 16 + l4 * 4 + j;
                if (row < nrows) {
                    float v = acc[m][n][j] + bbv;
                    Cb[(size_t)row * HD + col] = f2bf(v);
                    if (n == 0) { st00 += v; st01 = fmaf(v, v, st01); }
                    else        { st10 += v; st11 = fmaf(v, v, st11); }
                }
            }
        }
    }
#pragma unroll
    for (int d = 16; d < 64; d <<= 1) {
        st00 += __shfl_xor(st00, d);
        st01 += __shfl_xor(st01, d);
        st10 += __shfl_xor(st10, d);
        st11 += __shfl_xor(st11, d);
    }
    if (l4 == 0) {
        const int c0 = wc * 32 + l15, c1 = c0 + 16;
        sred[wr][c0][0] = st00; sred[wr][c0][1] = st01;
        sred[wr][c1][0] = st10; sred[wr][c1][1] = st11;
    }
    __syncthreads();
    if (t < 128) {
        float* so = statsOut + (blockIdx.x & (NBANK - 1)) * 256;
        atomicAdd(&so[t], sred[0][t][0] + sred[1][t][0]);
        atomicAdd(&so[128 + t], sred[0][t][1] + sred[1][t][1]);
    }
}

// ---------------- mean pool with BN+relu on the fly; optional h=relu(BN(c)) write ----

template <bool WR>
__global__ void pool_bn(const unsigned* __restrict__ hp, const int* __restrict__ gstart,
                        const float* __restrict__ stats, const float* __restrict__ gam,
                        const float* __restrict__ bet, float* __restrict__ pooled, int layerOff,
                        unsigned* __restrict__ hn) {
    __shared__ float2 red[8][64];
    const int g = blockIdx.x;
    const int tx = threadIdx.x;  // 512
    const int cp = tx & 63;
    const int q = tx >> 6;       // 0..7
    const float invn = 1.0f / (float)NN;
    const int c0 = 2 * cp, c1 = c0 + 1;
    float su0 = 0.f, sq0 = 0.f, su1 = 0.f, sq1 = 0.f;
#pragma unroll
    for (int b = 0; b < NBANK; ++b) {
        su0 += stats[b * 256 + c0];
        sq0 += stats[b * 256 + 128 + c0];
        su1 += stats[b * 256 + c1];
        sq1 += stats[b * 256 + 128 + c1];
    }
    float mu0 = su0 * invn;
    float va0 = sq0 * invn - mu0 * mu0;
    float sc0 = gam[c0] * rsqrtf(va0 + BN_EPS), sh0 = bet[c0] - mu0 * sc0;
    float mu1 = su1 * invn;
    float va1 = sq1 * invn - mu1 * mu1;
    float sc1 = gam[c1] * rsqrtf(va1 + BN_EPS), sh1 = bet[c1] - mu1 * sc1;

    const int s0 = gstart[g], s1 = gstart[g + 1];
    float a0 = 0.f, a1 = 0.f;
    for (int i = s0 + q; i < s1; i += 8) {
        unsigned u = hp[(size_t)i * 64 + cp];
        float v0 = fmaxf(fmaf(bflo(u), sc0, sh0), 0.f);
        float v1 = fmaxf(fmaf(bfhi(u), sc1, sh1), 0.f);
        if (WR) hn[(size_t)i * 64 + cp] = packbf2(v0, v1);
        a0 += v0;
        a1 += v1;
    }
    red[q][cp] = make_float2(a0, a1);
    __syncthreads();
    if (q == 0) {
        float r0 = 0.f, r1 = 0.f;
#pragma unroll
        for (int k = 0; k < 8; ++k) { r0 += red[k][cp].x; r1 += red[k][cp].y; }
        const int cnt = s1 - s0;
        const float fc = (cnt > 0) ? (float)cnt : 1.0f;
        *(float2*)&pooled[(size_t)g * (3 * HD) + layerOff + c0] = make_float2(r0 / fc, r1 / fc);
    }
}

// ---------------- final linear + row L2 normalize ----------------

__global__ void final_kernel(const float* __restrict__ pooled, const float* __restrict__ linW,
                             const float* __restrict__ linb, float* __restrict__ out) {
    __shared__ float p[3 * HD];
    const int g = blockIdx.x;
    const int o = threadIdx.x;  // 64 threads = 1 wave
    for (int k = o; k < 3 * HD; k += 64) p[k] = pooled[(size_t)g * (3 * HD) + k];
    __syncthreads();
    float acc = linb[o];
    const float* wrow = linW + (size_t)o * (3 * HD);
#pragma unroll 4
    for (int k = 0; k < 3 * HD; k += 4) {
        float4 wv = *(const float4*)(wrow + k);
        float4 pv = *(const float4*)(&p[k]);
        acc = fmaf(wv.x, pv.x, acc);
        acc = fmaf(wv.y, pv.y, acc);
        acc = fmaf(wv.z, pv.z, acc);
        acc = fmaf(wv.w, pv.w, acc);
    }
    float sq = acc * acc;
#pragma unroll
    for (int off = 32; off > 0; off >>= 1) sq += __shfl_xor(sq, off);
    float nrm = sqrtf(sq);
    nrm = fmaxf(nrm, 1e-12f);
    out[(size_t)g * OD + o] = acc / nrm;
}

// ---------------- launch ----------------

extern "C" void kernel_launch(void* const* d_in, const int* in_sizes, int n_in,
                              void* d_out, int out_size, void* d_ws, size_t ws_size,
                              hipStream_t stream) {
    const float* x    = (const float*)d_in[0];
    const int* ei     = (const int*)d_in[1];
    const int* batch  = (const int*)d_in[2];
    const float* W11  = (const float*)d_in[3];
    const float* b11  = (const float*)d_in[4];
    const float* W12  = (const float*)d_in[5];
    const float* b12  = (const float*)d_in[6];
    const float* g1   = (const float*)d_in[7];
    const float* be1  = (const float*)d_in[8];
    const float* W21  = (const float*)d_in[9];
    const float* b21  = (const float*)d_in[10];
    const float* W22  = (const float*)d_in[11];
    const float* b22  = (const float*)d_in[12];
    const float* g2   = (const float*)d_in[13];
    const float* be2  = (const float*)d_in[14];
    const float* W31  = (const float*)d_in[15];
    const float* b31  = (const float*)d_in[16];
    const float* W32  = (const float*)d_in[17];
    const float* b32  = (const float*)d_in[18];
    const float* g3   = (const float*)d_in[19];
    const float* be3  = (const float*)d_in[20];
    const float* linW = (const float*)d_in[21];
    const float* linb = (const float*)d_in[22];

    const int* src = ei;
    const int* dst = ei + NE;

    char* ws = (char*)d_ws;
    size_t off = 0;
    auto alloc = [&](size_t bytes) -> void* {
        void* p = ws + off;
        off += (bytes + 255) & ~(size_t)255;
        return p;
    };
    int* deg      = (int*)alloc((size_t)NN * 4);
    int* offsets  = (int*)alloc((size_t)(NN + 1) * 4);
    int* cursor   = (int*)alloc((size_t)NN * 4);
    int* srcs     = (int*)alloc((size_t)NE * 4);
    int* gstart   = (int*)alloc((size_t)(NG + 1) * 4);
    int* lexcl    = (int*)alloc((size_t)NN * 4);
    int* bsum     = (int*)alloc((size_t)NSB * 4);
    int* boff     = (int*)alloc((size_t)NSB * 4);
    float* stats  = (float*)alloc((size_t)3 * NBANK * 256 * 4);
    float* pooled = (float*)alloc((size_t)NG * 3 * HD * 4);
    unsigned short* xbf  = (unsigned short*)alloc((size_t)NN * HD * 2);
    unsigned short* cbf1 = (unsigned short*)alloc((size_t)NN * HD * 2);
    unsigned short* cbf2 = (unsigned short*)alloc((size_t)NN * HD * 2);
    unsigned short* hbf1 = (unsigned short*)alloc((size_t)NN * HD * 2);
    unsigned short* hbf2 = (unsigned short*)alloc((size_t)NN * HD * 2);
    unsigned short* wbf  = (unsigned short*)alloc((size_t)6 * HD * HD * 2);
    (void)ws_size; (void)n_in; (void)in_sizes; (void)out_size;

    // ---- conversions to bf16
    cvt_kernel<<<(NN * HD / 8 + 255) / 256, 256, 0, stream>>>(x, xbf, NN * HD / 8);
    cvt6_kernel<<<48, 256, 0, stream>>>(W11, W12, W21, W22, W31, W32, wbf);

    // ---- CSR build
    hipMemsetAsync(deg, 0, (size_t)NN * 4, stream);
    hist_kernel<<<(NE + 255) / 256, 256, 0, stream>>>(dst, deg, NE);
    local_scan_kernel<<<NSB, SCAN_BLK, 0, stream>>>(deg, lexcl, bsum, NN);
    scan_bsum_kernel<<<1, 64, 0, stream>>>(bsum, boff, offsets, NSB, NN);
    finalize_scan_kernel<<<(NN + 255) / 256, 256, 0, stream>>>(lexcl, boff, offsets, cursor, NN);
    fill_kernel<<<(NE + 255) / 256, 256, 0, stream>>>(src, dst, cursor, srcs, NE);
    gstart_kernel<<<(NN + 255) / 256, 256, 0, stream>>>(batch, gstart, NN, NG);

    hipMemsetAsync(stats, 0, (size_t)3 * NBANK * 256 * 4, stream);

    const int ginGrid = (NN + 63) / 64;  // 782

    const unsigned* xu  = (const unsigned*)xbf;
    const unsigned* c1u = (const unsigned*)cbf1;
    const unsigned* c2u = (const unsigned*)cbf2;
    const unsigned* h1u = (const unsigned*)hbf1;
    const unsigned* h2u = (const unsigned*)hbf2;

    float* st1 = stats;
    float* st2 = stats + NBANK * 256;
    float* st3 = stats + 2 * NBANK * 256;

    // L1: gather xbf -> cbf1 + st1; pool writes h1 = relu(BN1(c1))
    fused_gin<<<ginGrid, 512, 0, stream>>>(xu, offsets, srcs,
                                           wbf + 0 * HD * HD, b11, wbf + 1 * HD * HD, b12,
                                           cbf1, st1, NN);
    pool_bn<true><<<NG, 512, 0, stream>>>(c1u, gstart, st1, g1, be1, pooled, 0, (unsigned*)hbf1);

    // L2: gather h1 -> cbf2 + st2; pool writes h2
    fused_gin<<<ginGrid, 512, 0, stream>>>(h1u, offsets, srcs,
                                           wbf + 2 * HD * HD, b21, wbf + 3 * HD * HD, b22,
                                           cbf2, st2, NN);
    pool_bn<true><<<NG, 512, 0, stream>>>(c2u, gstart, st2, g2, be2, pooled, HD, (unsigned*)hbf2);

    // L3: gather h2 -> cbf1 (reuse) + st3; pool (no h write)
    fused_gin<<<ginGrid, 512, 0, stream>>>(h2u, offsets, srcs,
                                           wbf + 4 * HD * HD, b31, wbf + 5 * HD * HD, b32,
                                           cbf1, st3, NN);
    pool_bn<false><<<NG, 512, 0, stream>>>(c1u, gstart, st3, g3, be3, pooled, 2 * HD, nullptr);

    final_kernel<<<NG, OD, 0, stream>>>(pooled, linW, linb, (float*)d_out);
}

// Round 12
// 236.639 us; speedup vs baseline: 1.1451x; 1.1451x over previous
//
#include <hip/hip_runtime.h>

#define NN 50000
#define NE 600000
#define HD 128
#define NG 512
#define OD 64
#define BN_EPS 1e-5f

#define SCAN_BLK 1024
#define NSB ((NN + SCAN_BLK - 1) / SCAN_BLK)  // 49
#define ECAP 1536   // LDS edge-index capacity (mean 768/block; fallback if exceeded)
#define NBANK 8     // stats atomic shards

typedef __attribute__((ext_vector_type(8))) short bf16x8;
typedef __attribute__((ext_vector_type(4))) float f32x4;

__device__ __forceinline__ unsigned short f2bf(float f) {
    unsigned u = __builtin_bit_cast(unsigned, f);
    unsigned r = u + 0x7FFFu + ((u >> 16) & 1u);  // round-to-nearest-even
    return (unsigned short)(r >> 16);
}

__device__ __forceinline__ float bflo(unsigned u) { return __builtin_bit_cast(float, u << 16); }
__device__ __forceinline__ float bfhi(unsigned u) { return __builtin_bit_cast(float, u & 0xffff0000u); }

__device__ __forceinline__ unsigned packbf2(float x, float y) {
    return (unsigned)f2bf(x) | ((unsigned)f2bf(y) << 16);
}

// ---------------- fp32 -> bf16 bulk converts ----------------

__global__ void cvt_kernel(const float* __restrict__ src, unsigned short* __restrict__ dst, int n8) {
    int i = blockIdx.x * blockDim.x + threadIdx.x;
    if (i >= n8) return;
    float4 a = ((const float4*)src)[2 * i];
    float4 b = ((const float4*)src)[2 * i + 1];
    uint4 o;
    o.x = packbf2(a.x, a.y);
    o.y = packbf2(a.z, a.w);
    o.z = packbf2(b.x, b.y);
    o.w = packbf2(b.z, b.w);
    ((uint4*)dst)[i] = o;
}

__global__ void cvt6_kernel(const float* __restrict__ s0, const float* __restrict__ s1,
                            const float* __restrict__ s2, const float* __restrict__ s3,
                            const float* __restrict__ s4, const float* __restrict__ s5,
                            unsigned short* __restrict__ dst) {
    int i = blockIdx.x * blockDim.x + threadIdx.x;  // 0 .. 6*2048-1
    const int wsel = i >> 11;
    const int o8 = i & 2047;
    const float* sp = (wsel == 0) ? s0 : (wsel == 1) ? s1 : (wsel == 2) ? s2
                    : (wsel == 3) ? s3 : (wsel == 4) ? s4 : s5;
    float4 a = ((const float4*)sp)[2 * o8];
    float4 b = ((const float4*)sp)[2 * o8 + 1];
    uint4 o;
    o.x = packbf2(a.x, a.y);
    o.y = packbf2(a.z, a.w);
    o.z = packbf2(b.x, b.y);
    o.w = packbf2(b.z, b.w);
    ((uint4*)(dst + (size_t)wsel * HD * HD))[o8] = o;
}

// ---------------- CSR build ----------------

__global__ void hist_kernel(const int* __restrict__ dst, int* __restrict__ deg, int E) {
    int i = blockIdx.x * blockDim.x + threadIdx.x;
    if (i < E) atomicAdd(&deg[dst[i]], 1);
}

__global__ void local_scan_kernel(const int* __restrict__ deg, int* __restrict__ lexcl,
                                  int* __restrict__ bsum, int n) {
    __shared__ int part[SCAN_BLK];
    const int tid = threadIdx.x;
    const int i = blockIdx.x * SCAN_BLK + tid;
    int v = (i < n) ? deg[i] : 0;
    part[tid] = v;
    __syncthreads();
    int incl = v;
    for (int off = 1; off < SCAN_BLK; off <<= 1) {
        int t = (tid >= off) ? part[tid - off] : 0;
        __syncthreads();
        incl += t;
        part[tid] = incl;
        __syncthreads();
    }
    if (i < n) lexcl[i] = incl - v;
    if (tid == SCAN_BLK - 1) bsum[blockIdx.x] = incl;
}

__global__ void scan_bsum_kernel(const int* __restrict__ bsum, int* __restrict__ boff,
                                 int* __restrict__ offsets, int nb, int n) {
    const int tid = threadIdx.x;  // 64 threads
    int orig = (tid < nb) ? bsum[tid] : 0;
    int v = orig;
    for (int off = 1; off < 64; off <<= 1) {
        int t = __shfl_up(v, off);
        if (tid >= off) v += t;
    }
    if (tid < nb) boff[tid] = v - orig;
    if (tid == 63) offsets[n] = v;  // total = E
}

// finalize scan + graph-start boundaries in one pass
__global__ void finalize_gstart_kernel(const int* __restrict__ lexcl, const int* __restrict__ boff,
                                       int* __restrict__ offsets, int* __restrict__ cursor,
                                       const int* __restrict__ batch, int* __restrict__ gstart,
                                       int n, int G) {
    int i = blockIdx.x * blockDim.x + threadIdx.x;
    if (i >= n) return;
    int o = lexcl[i] + boff[i >> 10];
    offsets[i] = o;
    cursor[i] = o;
    int b = batch[i];
    int bp = (i == 0) ? -1 : batch[i - 1];
    for (int g = bp + 1; g <= b; ++g) gstart[g] = i;
    if (i == n - 1) {
        for (int g = b + 1; g <= G; ++g) gstart[g] = n;
    }
}

__global__ void fill_kernel(const int* __restrict__ src, const int* __restrict__ dst,
                            int* __restrict__ cursor, int* __restrict__ srcs, int E) {
    int i = blockIdx.x * blockDim.x + threadIdx.x;
    if (i < E) {
        int pos = atomicAdd(&cursor[dst[i]], 1);
        srcs[pos] = src[i];
    }
}

// ---------------- fused GIN layer ----------------
// z_i = h_i + sum_{j in N(i)} h_j  (h already BN+relu'd; pure sum gather)
// C = relu(z @ Wa^T + ba) @ Wb^T + bb  -> bf16 out + sharded column stats.
// 512 threads = 8 waves. Gather: lanes split 4 groups x 16 chunks; one uint4
// wave-load fetches FOUR rows (1 KB); <=16 items covered by 4 independent
// upfront loads (1 latency exposure/node).  [round-10 structure: best measured]

__global__ __launch_bounds__(512) void fused_gin(const unsigned* __restrict__ hp,
                                                 const int* __restrict__ offsets,
                                                 const int* __restrict__ srcs,
                                                 const unsigned short* __restrict__ WaBf,
                                                 const float* __restrict__ ba,
                                                 const unsigned short* __restrict__ WbBf,
                                                 const float* __restrict__ bb,
                                                 unsigned short* __restrict__ Cb,
                                                 float* __restrict__ statsOut,
                                                 int nrows) {
    __shared__ short SB[64 * 136];
    __shared__ int elds[ECAP];
    __shared__ float sred[2][128][2];

    const int t = threadIdx.x;
    const int lane = t & 63;
    const int w = t >> 6;        // wave 0..7
    const int g16 = lane >> 4;   // item slot 0..3
    const int c16 = lane & 15;   // 16B chunk within row
    const int row0 = blockIdx.x * 64;

    const int rend = (row0 + 64 < nrows) ? row0 + 64 : nrows;
    const int ebase = offsets[row0];
    const int cnt = offsets[rend] - ebase;
    const bool fast = (cnt <= ECAP);

    if (fast) {
        for (int k = t; k < cnt; k += 512) elds[k] = srcs[ebase + k];
    }
    __syncthreads();

    // ---- gather: wave w owns rows w*8 .. w*8+7, one node at a time
    for (int i = 0; i < 8; ++i) {
        const int r = w * 8 + i;
        const int grow = row0 + r;
        float a0 = 0.f, a1 = 0.f, a2 = 0.f, a3 = 0.f;
        float a4 = 0.f, a5 = 0.f, a6 = 0.f, a7 = 0.f;

        auto acc8 = [&](uint4 v) {
            a0 += bflo(v.x); a1 += bfhi(v.x);
            a2 += bflo(v.y); a3 += bfhi(v.y);
            a4 += bflo(v.z); a5 += bfhi(v.z);
            a6 += bflo(v.w); a7 += bfhi(v.w);
        };
        auto ld4 = [&](int idx) -> uint4 {
            return ((const uint4*)(hp + (size_t)idx * 64))[c16];
        };

        if (grow < nrows) {
            const int jb = offsets[grow];
            const int items = offsets[grow + 1] - jb + 1;  // self + edges
            if (fast) {
                const int j0 = jb - ebase;
                uint4 v0 = {0, 0, 0, 0}, v1 = {0, 0, 0, 0}, v2 = {0, 0, 0, 0}, v3 = {0, 0, 0, 0};
                {
                    const int it = g16;
                    if (it < items) v0 = ld4(it == 0 ? grow : elds[j0 + it - 1]);
                }
                {
                    const int it = 4 + g16;
                    if (it < items) v1 = ld4(elds[j0 + it - 1]);
                }
                {
                    const int it = 8 + g16;
                    if (it < items) v2 = ld4(elds[j0 + it - 1]);
                }
                {
                    const int it = 12 + g16;
                    if (it < items) v3 = ld4(elds[j0 + it - 1]);
                }
                acc8(v0); acc8(v1); acc8(v2); acc8(v3);
                for (int base = 16; base < items; base += 4) {
                    const int it = base + g16;
                    uint4 v = {0, 0, 0, 0};
                    if (it < items) v = ld4(elds[j0 + it - 1]);
                    acc8(v);
                }
            } else {
                for (int base = 0; base < items; base += 4) {
                    const int it = base + g16;
                    uint4 v = {0, 0, 0, 0};
                    if (it < items) v = ld4(it == 0 ? grow : srcs[jb + it - 1]);
                    acc8(v);
                }
            }
        }
        a0 += __shfl_xor(a0, 16); a1 += __shfl_xor(a1, 16);
        a2 += __shfl_xor(a2, 16); a3 += __shfl_xor(a3, 16);
        a4 += __shfl_xor(a4, 16); a5 += __shfl_xor(a5, 16);
        a6 += __shfl_xor(a6, 16); a7 += __shfl_xor(a7, 16);
        a0 += __shfl_xor(a0, 32); a1 += __shfl_xor(a1, 32);
        a2 += __shfl_xor(a2, 32); a3 += __shfl_xor(a3, 32);
        a4 += __shfl_xor(a4, 32); a5 += __shfl_xor(a5, 32);
        a6 += __shfl_xor(a6, 32); a7 += __shfl_xor(a7, 32);
        if (g16 == 0) {
            uint4 o;
            o.x = packbf2(a0, a1);
            o.y = packbf2(a2, a3);
            o.z = packbf2(a4, a5);
            o.w = packbf2(a6, a7);
            *(uint4*)&SB[r * 136 + c16 * 8] = o;
        }
    }
    __syncthreads();  // SB holds A

    const int wr = w >> 2;     // row half (32 rows)
    const int wc = w & 3;      // col quarter (32 cols)
    const int l15 = lane & 15;
    const int l4 = lane >> 4;  // 0..3

    // ---- MFMA pass 1: t = A @ Wa^T
    f32x4 acc[2][2];
#pragma unroll
    for (int m = 0; m < 2; ++m)
#pragma unroll
        for (int n = 0; n < 2; ++n) acc[m][n] = (f32x4){0.f, 0.f, 0.f, 0.f};

#pragma unroll
    for (int kk = 0; kk < 4; ++kk) {
        bf16x8 af[2], bfr[2];
#pragma unroll
        for (int m = 0; m < 2; ++m)
            af[m] = *(const bf16x8*)&SB[(wr * 32 + m * 16 + l15) * 136 + kk * 32 + l4 * 8];
#pragma unroll
        for (int n = 0; n < 2; ++n)
            bfr[n] = *(const bf16x8*)(WaBf + (size_t)(wc * 32 + n * 16 + l15) * HD + kk * 32 + l4 * 8);
#pragma unroll
        for (int m = 0; m < 2; ++m)
#pragma unroll
            for (int n = 0; n < 2; ++n)
                acc[m][n] = __builtin_amdgcn_mfma_f32_16x16x32_bf16(af[m], bfr[n], acc[m][n], 0, 0, 0);
    }
    __syncthreads();  // pass-1 SB reads complete

    // epilogue 1: relu(t + ba) -> SB (as A2, bf16)
#pragma unroll
    for (int n = 0; n < 2; ++n) {
        const int col = wc * 32 + n * 16 + l15;
        const float bav = ba[col];
#pragma unroll
        for (int m = 0; m < 2; ++m) {
#pragma unroll
            for (int j = 0; j < 4; ++j) {
                const int row = wr * 32 + m * 16 + l4 * 4 + j;
                SB[row * 136 + col] = (short)f2bf(fmaxf(acc[m][n][j] + bav, 0.f));
            }
        }
    }
    __syncthreads();  // A2 visible

    // ---- MFMA pass 2: C = A2 @ Wb^T
#pragma unroll
    for (int m = 0; m < 2; ++m)
#pragma unroll
        for (int n = 0; n < 2; ++n) acc[m][n] = (f32x4){0.f, 0.f, 0.f, 0.f};

#pragma unroll
    for (int kk = 0; kk < 4; ++kk) {
        bf16x8 af[2], bfr[2];
#pragma unroll
        for (int m = 0; m < 2; ++m)
            af[m] = *(const bf16x8*)&SB[(wr * 32 + m * 16 + l15) * 136 + kk * 32 + l4 * 8];
#pragma unroll
        for (int n = 0; n < 2; ++n)
            bfr[n] = *(const bf16x8*)(WbBf + (size_t)(wc * 32 + n * 16 + l15) * HD + kk * 32 + l4 * 8);
#pragma unroll
        for (int m = 0; m < 2; ++m)
#pragma unroll
            for (int n = 0; n < 2; ++n)
                acc[m][n] = __builtin_amdgcn_mfma_f32_16x16x32_bf16(af[m], bfr[n], acc[m][n], 0, 0, 0);
    }

    // epilogue 2: Cb = bf16(acc + bb), plus per-column stats partials
    float st00 = 0.f, st01 = 0.f, st10 = 0.f, st11 = 0.f;
#pragma unroll
    for (int n = 0; n < 2; ++n) {
        const int col = wc * 32 + n * 16 + l15;
        const float bbv = bb[col];
#pragma unroll
        for (int m = 0; m < 2; ++m) {
#pragma unroll
            for (int j = 0; j < 4; ++j) {
                const int row = row0 + wr * 32 + m * 16 + l4 * 4 + j;
                if (row < nrows) {
                    float v = acc[m][n][j] + bbv;
                    Cb[(size_t)row * HD + col] = f2bf(v);
                    if (n == 0) { st00 += v; st01 = fmaf(v, v, st01); }
                    else        { st10 += v; st11 = fmaf(v, v, st11); }
                }
            }
        }
    }
#pragma unroll
    for (int d = 16; d < 64; d <<= 1) {
        st00 += __shfl_xor(st00, d);
        st01 += __shfl_xor(st01, d);
        st10 += __shfl_xor(st10, d);
        st11 += __shfl_xor(st11, d);
    }
    if (l4 == 0) {
        const int c0 = wc * 32 + l15, c1 = c0 + 16;
        sred[wr][c0][0] = st00; sred[wr][c0][1] = st01;
        sred[wr][c1][0] = st10; sred[wr][c1][1] = st11;
    }
    __syncthreads();
    if (t < 128) {
        float* so = statsOut + (blockIdx.x & (NBANK - 1)) * 256;
        atomicAdd(&so[t], sred[0][t][0] + sred[1][t][0]);
        atomicAdd(&so[128 + t], sred[0][t][1] + sred[1][t][1]);
    }
}

// ---------------- mean pool with BN+relu on the fly; optional h=relu(BN(c)) write ----
// 512 threads: chunk = tx&15 (uint4 = 8 channels), row slice q = tx>>4 (0..31).

template <bool WR>
__global__ void pool_bn(const unsigned* __restrict__ hp, const int* __restrict__ gstart,
                        const float* __restrict__ stats, const float* __restrict__ gam,
                        const float* __restrict__ bet, float* __restrict__ pooled, int layerOff,
                        unsigned* __restrict__ hn) {
    __shared__ float sstat[256];
    __shared__ float wred[8][16][8];
    __shared__ float fin[128];

    const int g = blockIdx.x;
    const int tx = threadIdx.x;   // 512
    const int ch = tx & 15;       // 16B chunk -> channels ch*8 .. ch*8+7
    const int q = tx >> 4;        // 0..31
    const int w = tx >> 6;        // wave
    const int lane = tx & 63;

    // reduce stats shards cooperatively
    for (int k = tx; k < 256; k += 512) {
        float s = 0.f;
#pragma unroll
        for (int b = 0; b < NBANK; ++b) s += stats[b * 256 + k];
        sstat[k] = s;
    }
    __syncthreads();

    const float invn = 1.0f / (float)NN;
    float sc[8], sh[8];
#pragma unroll
    for (int k = 0; k < 8; ++k) {
        const int c = ch * 8 + k;
        float mu = sstat[c] * invn;
        float va = sstat[128 + c] * invn - mu * mu;
        sc[k] = gam[c] * rsqrtf(va + BN_EPS);
        sh[k] = bet[c] - mu * sc[k];
    }

    const int s0 = gstart[g], s1 = gstart[g + 1];
    float a[8];
#pragma unroll
    for (int k = 0; k < 8; ++k) a[k] = 0.f;

    for (int i = s0 + q; i < s1; i += 32) {
        uint4 u = ((const uint4*)(hp + (size_t)i * 64))[ch];
        float v0 = fmaxf(fmaf(bflo(u.x), sc[0], sh[0]), 0.f);
        float v1 = fmaxf(fmaf(bfhi(u.x), sc[1], sh[1]), 0.f);
        float v2 = fmaxf(fmaf(bflo(u.y), sc[2], sh[2]), 0.f);
        float v3 = fmaxf(fmaf(bfhi(u.y), sc[3], sh[3]), 0.f);
        float v4 = fmaxf(fmaf(bflo(u.z), sc[4], sh[4]), 0.f);
        float v5 = fmaxf(fmaf(bfhi(u.z), sc[5], sh[5]), 0.f);
        float v6 = fmaxf(fmaf(bflo(u.w), sc[6], sh[6]), 0.f);
        float v7 = fmaxf(fmaf(bfhi(u.w), sc[7], sh[7]), 0.f);
        if (WR) {
            uint4 o;
            o.x = packbf2(v0, v1);
            o.y = packbf2(v2, v3);
            o.z = packbf2(v4, v5);
            o.w = packbf2(v6, v7);
            ((uint4*)(hn + (size_t)i * 64))[ch] = o;
        }
        a[0] += v0; a[1] += v1; a[2] += v2; a[3] += v3;
        a[4] += v4; a[5] += v5; a[6] += v6; a[7] += v7;
    }

    // reduce 4 q-slices within each wave (lane bits 4,5)
#pragma unroll
    for (int k = 0; k < 8; ++k) {
        a[k] += __shfl_xor(a[k], 16);
        a[k] += __shfl_xor(a[k], 32);
    }
    if ((lane >> 4) == 0) {
#pragma unroll
        for (int k = 0; k < 8; ++k) wred[w][ch][k] = a[k];
    }
    __syncthreads();

    const int cnt = s1 - s0;
    const float fc = (cnt > 0) ? (float)cnt : 1.0f;
    if (tx < 128) {
        float r = 0.f;
#pragma unroll
        for (int ww = 0; ww < 8; ++ww) r += wred[ww][tx >> 3][tx & 7];
        fin[tx] = r / fc;
    }
    __syncthreads();
    if (tx < 32) {
        float4 v = *(const float4*)&fin[tx * 4];
        *(float4*)&pooled[(size_t)g * (3 * HD) + layerOff + tx * 4] = v;
    }
}

// ---------------- final linear + row L2 normalize ----------------

__global__ void final_kernel(const float* __restrict__ pooled, const float* __restrict__ linW,
                             const float* __restrict__ linb, float* __restrict__ out) {
    __shared__ float p[3 * HD];
    const int g = blockIdx.x;
    const int o = threadIdx.x;  // 64 threads = 1 wave
    for (int k = o; k < 3 * HD; k += 64) p[k] = pooled[(size_t)g * (3 * HD) + k];
    __syncthreads();
    float acc = linb[o];
    const float* wrow = linW + (size_t)o * (3 * HD);
#pragma unroll 4
    for (int k = 0; k < 3 * HD; k += 4) {
        float4 wv = *(const float4*)(wrow + k);
        float4 pv = *(const float4*)(&p[k]);
        acc = fmaf(wv.x, pv.x, acc);
        acc = fmaf(wv.y, pv.y, acc);
        acc = fmaf(wv.z, pv.z, acc);
        acc = fmaf(wv.w, pv.w, acc);
    }
    float sq = acc * acc;
#pragma unroll
    for (int off = 32; off > 0; off >>= 1) sq += __shfl_xor(sq, off);
    float nrm = sqrtf(sq);
    nrm = fmaxf(nrm, 1e-12f);
    out[(size_t)g * OD + o] = acc / nrm;
}

// ---------------- launch ----------------

extern "C" void kernel_launch(void* const* d_in, const int* in_sizes, int n_in,
                              void* d_out, int out_size, void* d_ws, size_t ws_size,
                              hipStream_t stream) {
    const float* x    = (const float*)d_in[0];
    const int* ei     = (const int*)d_in[1];
    const int* batch  = (const int*)d_in[2];
    const float* W11  = (const float*)d_in[3];
    const float* b11  = (const float*)d_in[4];
    const float* W12  = (const float*)d_in[5];
    const float* b12  = (const float*)d_in[6];
    const float* g1   = (const float*)d_in[7];
    const float* be1  = (const float*)d_in[8];
    const float* W21  = (const float*)d_in[9];
    const float* b21  = (const float*)d_in[10];
    const float* W22  = (const float*)d_in[11];
    const float* b22  = (const float*)d_in[12];
    const float* g2   = (const float*)d_in[13];
    const float* be2  = (const float*)d_in[14];
    const float* W31  = (const float*)d_in[15];
    const float* b31  = (const float*)d_in[16];
    const float* W32  = (const float*)d_in[17];
    const float* b32  = (const float*)d_in[18];
    const float* g3   = (const float*)d_in[19];
    const float* be3  = (const float*)d_in[20];
    const float* linW = (const float*)d_in[21];
    const float* linb = (const float*)d_in[22];

    const int* src = ei;
    const int* dst = ei + NE;

    char* ws = (char*)d_ws;
    size_t off = 0;
    auto alloc = [&](size_t bytes) -> void* {
        void* p = ws + off;
        off += (bytes + 255) & ~(size_t)255;
        return p;
    };
    int* deg      = (int*)alloc((size_t)NN * 4);
    int* offsets  = (int*)alloc((size_t)(NN + 1) * 4);
    int* cursor   = (int*)alloc((size_t)NN * 4);
    int* srcs     = (int*)alloc((size_t)NE * 4);
    int* gstart   = (int*)alloc((size_t)(NG + 1) * 4);
    int* lexcl    = (int*)alloc((size_t)NN * 4);
    int* bsum     = (int*)alloc((size_t)NSB * 4);
    int* boff     = (int*)alloc((size_t)NSB * 4);
    float* stats  = (float*)alloc((size_t)3 * NBANK * 256 * 4);
    float* pooled = (float*)alloc((size_t)NG * 3 * HD * 4);
    unsigned short* xbf  = (unsigned short*)alloc((size_t)NN * HD * 2);
    unsigned short* cbf1 = (unsigned short*)alloc((size_t)NN * HD * 2);
    unsigned short* cbf2 = (unsigned short*)alloc((size_t)NN * HD * 2);
    unsigned short* hbf1 = (unsigned short*)alloc((size_t)NN * HD * 2);
    unsigned short* hbf2 = (unsigned short*)alloc((size_t)NN * HD * 2);
    unsigned short* wbf  = (unsigned short*)alloc((size_t)6 * HD * HD * 2);
    (void)ws_size; (void)n_in; (void)in_sizes; (void)out_size;

    // ---- conversions to bf16
    cvt_kernel<<<(NN * HD / 8 + 255) / 256, 256, 0, stream>>>(x, xbf, NN * HD / 8);
    cvt6_kernel<<<48, 256, 0, stream>>>(W11, W12, W21, W22, W31, W32, wbf);

    // ---- CSR build
    hipMemsetAsync(deg, 0, (size_t)NN * 4, stream);
    hist_kernel<<<(NE + 255) / 256, 256, 0, stream>>>(dst, deg, NE);
    local_scan_kernel<<<NSB, SCAN_BLK, 0, stream>>>(deg, lexcl, bsum, NN);
    scan_bsum_kernel<<<1, 64, 0, stream>>>(bsum, boff, offsets, NSB, NN);
    finalize_gstart_kernel<<<(NN + 255) / 256, 256, 0, stream>>>(lexcl, boff, offsets, cursor,
                                                                 batch, gstart, NN, NG);
    fill_kernel<<<(NE + 255) / 256, 256, 0, stream>>>(src, dst, cursor, srcs, NE);

    hipMemsetAsync(stats, 0, (size_t)3 * NBANK * 256 * 4, stream);

    const int ginGrid = (NN + 63) / 64;  // 782

    const unsigned* xu  = (const unsigned*)xbf;
    const unsigned* c1u = (const unsigned*)cbf1;
    const unsigned* c2u = (const unsigned*)cbf2;
    const unsigned* h1u = (const unsigned*)hbf1;
    const unsigned* h2u = (const unsigned*)hbf2;

    float* st1 = stats;
    float* st2 = stats + NBANK * 256;
    float* st3 = stats + 2 * NBANK * 256;

    // L1: gather xbf -> cbf1 + st1; pool writes h1 = relu(BN1(c1))
    fused_gin<<<ginGrid, 512, 0, stream>>>(xu, offsets, srcs,
                                           wbf + 0 * HD * HD, b11, wbf + 1 * HD * HD, b12,
                                           cbf1, st1, NN);
    pool_bn<true><<<NG, 512, 0, stream>>>(c1u, gstart, st1, g1, be1, pooled, 0, (unsigned*)hbf1);

    // L2: gather h1 -> cbf2 + st2; pool writes h2
    fused_gin<<<ginGrid, 512, 0, stream>>>(h1u, offsets, srcs,
                                           wbf + 2 * HD * HD, b21, wbf + 3 * HD * HD, b22,
                                           cbf2, st2, NN);
    pool_bn<true><<<NG, 512, 0, stream>>>(c2u, gstart, st2, g2, be2, pooled, HD, (unsigned*)hbf2);

    // L3: gather h2 -> cbf1 (reuse) + st3; pool (no h write)
    fused_gin<<<ginGrid, 512, 0, stream>>>(h2u, offsets, srcs,
                                           wbf + 4 * HD * HD, b31, wbf + 5 * HD * HD, b32,
                                           cbf1, st3, NN);
    pool_bn<false><<<NG, 512, 0, stream>>>(c1u, gstart, st3, g3, be3, pooled, 2 * HD, nullptr);

    final_kernel<<<NG, OD, 0, stream>>>(pooled, linW, linb, (float*)d_out);
}